// Round 1
// baseline (891.623 us; speedup 1.0000x reference)
//
#include <hip/hip_runtime.h>

#define NB 8
#define TQv 2048
#define TKv 2048
#define FD 1024
#define HD 1024

typedef __attribute__((ext_vector_type(8))) short short8;
typedef __attribute__((ext_vector_type(8))) _Float16 half8;
typedef __attribute__((ext_vector_type(4))) float f32x4;

// round-to-nearest-even fp32 -> bf16 (finite inputs only)
__device__ __forceinline__ short f2bf(float f) {
    union { float f; unsigned u; } v; v.f = f;
    unsigned r = v.u + 0x7FFFu + ((v.u >> 16) & 1u);
    return (short)(r >> 16);
}

// ---- GEMM building blocks: NT form, C[m][n] = sum_k A[m][k] * Bt[n][k] ----
// tile 64(M) x 64(N), BK=32, block = 256 threads = 4 waves; wave w does rows w*16..w*16+15.

// stage 64x32 fp32 tile -> LDS bf16 (each thread: 8 floats = 2x float4, 1x ds_write_b128)
__device__ __forceinline__ void stage_a_f32(short* __restrict__ As, const float* __restrict__ A,
                                            int lda, int tid) {
    int row = tid >> 2;
    int col = (tid & 3) << 3;
    const float4* src = (const float4*)(A + (size_t)row * lda + col);
    float4 x0 = src[0], x1 = src[1];
    short8 v;
    v[0] = f2bf(x0.x); v[1] = f2bf(x0.y); v[2] = f2bf(x0.z); v[3] = f2bf(x0.w);
    v[4] = f2bf(x1.x); v[5] = f2bf(x1.y); v[6] = f2bf(x1.z); v[7] = f2bf(x1.w);
    *(short8*)(As + row * 32 + col) = v;
}

// stage 64x32 bf16 tile -> LDS (each thread: 1x 16B load, 1x ds_write_b128)
__device__ __forceinline__ void stage_bf16(short* __restrict__ Ds, const short* __restrict__ S,
                                           int ld, int tid) {
    int row = tid >> 2;
    int col = (tid & 3) << 3;
    *(short8*)(Ds + row * 32 + col) = *(const short8*)(S + (size_t)row * ld + col);
}

// one BK=32 step: wave computes 16x64 via 4 MFMAs
// A-frag: A[m=lane&15][k=quad*8+j]; B-frag: Bt[n=lane&15][k=quad*8+j]; both contiguous 16B
__device__ __forceinline__ void mfma_tile(const short* __restrict__ As, const short* __restrict__ Bs,
                                          int wave, int lane, f32x4* acc) {
    int r16 = lane & 15;
    int q8 = (lane >> 4) << 3;
    short8 a = *(const short8*)(As + (wave * 16 + r16) * 32 + q8);
#pragma unroll
    for (int c = 0; c < 4; ++c) {
        short8 b = *(const short8*)(Bs + (c * 16 + r16) * 32 + q8);
        acc[c] = __builtin_amdgcn_mfma_f32_16x16x32_bf16(a, b, acc[c], 0, 0, 0);
    }
}

// ---- kernel 0: W[F][H] fp32 -> Wt[H][F] bf16, z picks Wq/Wk/Wv ----
__global__ __launch_bounds__(256) void wtrans_kernel(const float* __restrict__ Wq,
                                                     const float* __restrict__ Wk,
                                                     const float* __restrict__ Wv,
                                                     short* __restrict__ Wt) {
    __shared__ float tile[32][33];
    const float* W = (blockIdx.z == 0) ? Wq : (blockIdx.z == 1) ? Wk : Wv;
    short* dst = Wt + (size_t)blockIdx.z * HD * FD;
    int h0 = blockIdx.x * 32, f0 = blockIdx.y * 32;
    int tx = threadIdx.x, ty = threadIdx.y;
    for (int j = ty; j < 32; j += 8)
        tile[j][tx] = W[(size_t)(f0 + j) * HD + h0 + tx];
    __syncthreads();
    for (int j = ty; j < 32; j += 8)
        dst[(size_t)(h0 + j) * FD + f0 + tx] = f2bf(tile[tx][j]);
}

// ---- kernel 1: fused projections. z=0: Q=query@Wq+bq; z=1: K=enc@Wk+bk; z=2: Vt=(enc@Wv+bv)^T ----
__global__ __launch_bounds__(256) void proj_kernel(const float* __restrict__ Xq,
                                                   const float* __restrict__ Xe,
                                                   const short* __restrict__ Wt3,
                                                   const float* __restrict__ bq,
                                                   const float* __restrict__ bk,
                                                   const float* __restrict__ bv,
                                                   short* __restrict__ Q, short* __restrict__ K,
                                                   short* __restrict__ Vt) {
    __shared__ short As[64 * 32];
    __shared__ short Bs[64 * 32];
    int tid = threadIdx.x;
    int wave = tid >> 6, lane = tid & 63;
    int p = blockIdx.z;
    const float* X = (p == 0) ? Xq : Xe;
    const short* Wt = Wt3 + (size_t)p * HD * FD;
    const float* bias = (p == 0) ? bq : (p == 1) ? bk : bv;
    int tile_m = blockIdx.x * 64;  // over M = NB*TQv = 16384
    int tile_n = blockIdx.y * 64;  // over HD
    f32x4 acc[4] = {{0.f, 0.f, 0.f, 0.f}, {0.f, 0.f, 0.f, 0.f},
                    {0.f, 0.f, 0.f, 0.f}, {0.f, 0.f, 0.f, 0.f}};
    for (int k0 = 0; k0 < FD; k0 += 32) {
        __syncthreads();
        stage_a_f32(As, X + (size_t)tile_m * FD + k0, FD, tid);
        stage_bf16(Bs, Wt + (size_t)tile_n * FD + k0, FD, tid);
        __syncthreads();
        mfma_tile(As, Bs, wave, lane, acc);
    }
    int qr = (lane >> 4) << 2;
    int cn = lane & 15;
#pragma unroll
    for (int c = 0; c < 4; ++c) {
        int gn = tile_n + c * 16 + cn;
        float bv_ = bias[gn];
#pragma unroll
        for (int r = 0; r < 4; ++r) {
            int gm = tile_m + wave * 16 + qr + r;
            short val = f2bf(acc[c][r] + bv_);
            if (p == 0) {
                Q[(size_t)gm * HD + gn] = val;
            } else if (p == 1) {
                K[(size_t)gm * HD + gn] = val;
            } else {
                int b = gm >> 11, t = gm & (TKv - 1);
                Vt[((size_t)b * HD + gn) * TKv + t] = val;
            }
        }
    }
}

// ---- kernel 2: S[b][q][k] = (Q[b,q,:] . K[b,k,:]) / 32, fp16 out ----
__global__ __launch_bounds__(256) void score_kernel(const short* __restrict__ Q,
                                                    const short* __restrict__ K,
                                                    short* __restrict__ S) {
    __shared__ short As[64 * 32];
    __shared__ short Bs[64 * 32];
    int tid = threadIdx.x;
    int wave = tid >> 6, lane = tid & 63;
    int b = blockIdx.z;
    int tile_m = blockIdx.x * 64;  // over TQv
    int tile_n = blockIdx.y * 64;  // over TKv
    const short* Aq = Q + (size_t)b * TQv * HD;
    const short* Bk = K + (size_t)b * TKv * HD;
    f32x4 acc[4] = {{0.f, 0.f, 0.f, 0.f}, {0.f, 0.f, 0.f, 0.f},
                    {0.f, 0.f, 0.f, 0.f}, {0.f, 0.f, 0.f, 0.f}};
    for (int k0 = 0; k0 < HD; k0 += 32) {
        __syncthreads();
        stage_bf16(As, Aq + (size_t)tile_m * HD + k0, HD, tid);
        stage_bf16(Bs, Bk + (size_t)tile_n * HD + k0, HD, tid);
        __syncthreads();
        mfma_tile(As, Bs, wave, lane, acc);
    }
    int qr = (lane >> 4) << 2;
    int cn = lane & 15;
    short* Sb = S + (size_t)b * TQv * TKv;
#pragma unroll
    for (int c = 0; c < 4; ++c) {
        int gn = tile_n + c * 16 + cn;
#pragma unroll
        for (int r = 0; r < 4; ++r) {
            int gm = tile_m + wave * 16 + qr + r;
            union { _Float16 h; short s; } cv;
            cv.h = (_Float16)(acc[c][r] * 0.03125f);
            Sb[(size_t)gm * TKv + gn] = cv.s;
        }
    }
}

// ---- kernel 3: masked softmax over each row of S (fp16 in), writes P (bf16) in place ----
__global__ __launch_bounds__(256) void softmax_kernel(const int* __restrict__ mask,
                                                      short* __restrict__ S) {
    __shared__ float red[256];
    int row = blockIdx.x;  // 0 .. NB*TQv-1
    int tid = threadIdx.x;
    const int* mrow = mask + (size_t)row * TKv;
    short* srow = S + (size_t)row * TKv;
    half8 hv = *(const half8*)(srow + tid * 8);
    int4 m0 = *(const int4*)(mrow + tid * 8);
    int4 m1 = *(const int4*)(mrow + tid * 8 + 4);
    int mk[8] = {m0.x, m0.y, m0.z, m0.w, m1.x, m1.y, m1.z, m1.w};
    float v[8];
#pragma unroll
    for (int i = 0; i < 8; ++i) v[i] = (float)hv[i];
    float lmax = -1e30f;
#pragma unroll
    for (int i = 0; i < 8; ++i)
        if (mk[i]) lmax = fmaxf(lmax, v[i]);
    red[tid] = lmax;
    __syncthreads();
    for (int s = 128; s > 0; s >>= 1) {
        if (tid < s) red[tid] = fmaxf(red[tid], red[tid + s]);
        __syncthreads();
    }
    float rmax = red[0];
    __syncthreads();
    float lsum = 0.f;
#pragma unroll
    for (int i = 0; i < 8; ++i) {
        float e = mk[i] ? exp2f((v[i] - rmax) * 1.44269504f) : 0.f;
        v[i] = e;
        lsum += e;
    }
    red[tid] = lsum;
    __syncthreads();
    for (int s = 128; s > 0; s >>= 1) {
        if (tid < s) red[tid] += red[tid + s];
        __syncthreads();
    }
    float rsum = red[0];
    float inv = (rsum > 0.f) ? 1.f / rsum : 0.f;
    short8 o;
#pragma unroll
    for (int i = 0; i < 8; ++i) o[i] = f2bf(v[i] * inv);
    *(short8*)(srow + tid * 8) = o;
}

// ---- kernel 4: O[b][q][h] = sum_k P[b,q,k] * Vt[b,h,k], fp32 out ----
__global__ __launch_bounds__(256) void pv_kernel(const short* __restrict__ P,
                                                 const short* __restrict__ Vt,
                                                 float* __restrict__ Out) {
    __shared__ short As[64 * 32];
    __shared__ short Bs[64 * 32];
    int tid = threadIdx.x;
    int wave = tid >> 6, lane = tid & 63;
    int b = blockIdx.z;
    int tile_m = blockIdx.x * 64;  // over TQv
    int tile_n = blockIdx.y * 64;  // over HD
    const short* Ap = P + (size_t)b * TQv * TKv;
    const short* Bv = Vt + (size_t)b * HD * TKv;
    f32x4 acc[4] = {{0.f, 0.f, 0.f, 0.f}, {0.f, 0.f, 0.f, 0.f},
                    {0.f, 0.f, 0.f, 0.f}, {0.f, 0.f, 0.f, 0.f}};
    for (int k0 = 0; k0 < TKv; k0 += 32) {
        __syncthreads();
        stage_bf16(As, Ap + (size_t)tile_m * TKv + k0, TKv, tid);
        stage_bf16(Bs, Bv + (size_t)tile_n * TKv + k0, TKv, tid);
        __syncthreads();
        mfma_tile(As, Bs, wave, lane, acc);
    }
    int qr = (lane >> 4) << 2;
    int cn = lane & 15;
    float* Ob = Out + (size_t)b * TQv * HD;
#pragma unroll
    for (int c = 0; c < 4; ++c) {
        int gn = tile_n + c * 16 + cn;
#pragma unroll
        for (int r = 0; r < 4; ++r) {
            int gm = tile_m + wave * 16 + qr + r;
            Ob[(size_t)gm * HD + gn] = acc[c][r];
        }
    }
}

extern "C" void kernel_launch(void* const* d_in, const int* in_sizes, int n_in,
                              void* d_out, int out_size, void* d_ws, size_t ws_size,
                              hipStream_t stream) {
    const float* query = (const float*)d_in[0];
    const float* enc   = (const float*)d_in[1];
    const int*   mask  = (const int*)d_in[2];
    const float* Wq    = (const float*)d_in[3];
    const float* bq    = (const float*)d_in[4];
    const float* Wk    = (const float*)d_in[5];
    const float* bk    = (const float*)d_in[6];
    const float* Wv    = (const float*)d_in[7];
    const float* bv    = (const float*)d_in[8];
    float* out = (float*)d_out;

    // workspace layout (bytes); total 174,063,616
    char* ws = (char*)d_ws;
    short* Wt = (short*)(ws);                  // 3 x [HD][FD] bf16   = 6,291,456
    short* Qb = (short*)(ws + 6291456);        // [NB*TQv][HD] bf16   = 33,554,432
    short* Kb = (short*)(ws + 39845888);       // [NB*TKv][HD] bf16   = 33,554,432
    short* Vt = (short*)(ws + 73400320);       // [NB][HD][TKv] bf16  = 33,554,432
    short* S  = (short*)(ws + 106954752);      // [NB][TQv][TKv] fp16 -> bf16 P in place = 67,108,864
    (void)in_sizes; (void)n_in; (void)out_size; (void)ws_size;

    wtrans_kernel<<<dim3(32, 32, 3), dim3(32, 8), 0, stream>>>(Wq, Wk, Wv, Wt);
    proj_kernel<<<dim3(256, 16, 3), 256, 0, stream>>>(query, enc, Wt, bq, bk, bv, Qb, Kb, Vt);
    score_kernel<<<dim3(32, 32, 8), 256, 0, stream>>>(Qb, Kb, S);
    softmax_kernel<<<dim3(NB * TQv), 256, 0, stream>>>(mask, S);
    pv_kernel<<<dim3(32, 16, 8), 256, 0, stream>>>(S, Vt, out);
}

// Round 2
// 683.122 us; speedup vs baseline: 1.3052x; 1.3052x over previous
//
#include <hip/hip_runtime.h>

#define NB 8
#define TQv 2048
#define TKv 2048
#define FD 1024
#define HD 1024

typedef __attribute__((ext_vector_type(8))) short short8;
typedef __attribute__((ext_vector_type(8))) _Float16 half8;
typedef __attribute__((ext_vector_type(4))) float f32x4;

// round-to-nearest-even fp32 -> bf16 (finite inputs only)
__device__ __forceinline__ short f2bf(float f) {
    union { float f; unsigned u; } v; v.f = f;
    unsigned r = v.u + 0x7FFFu + ((v.u >> 16) & 1u);
    return (short)(r >> 16);
}

// async 16B global -> LDS (global_load_lds_dwordx4). LDS dest is wave-uniform
// base + lane*16; our LDS tile is exactly lane-order contiguous (no padding).
__device__ __forceinline__ void async16(const short* g, short* l) {
    __builtin_amdgcn_global_load_lds(
        (const __attribute__((address_space(1))) unsigned int*)g,
        (__attribute__((address_space(3))) unsigned int*)l, 16, 0, 0);
}

// ---- m97-style GEMM core: NT form, C[m][n] = sum_k A[m][k] * Bt[n][k] ----
// tile 128(M) x 128(N), BK=32, 256 threads = 4 waves (2x2), acc 4x4 per wave.
// LDS: As[128][32], Bs[128][32] bf16, 8KB each, row stride 64B (= 4 lanes x 16B).
__device__ __forceinline__ void gemm128_core(const short* __restrict__ A, int lda,
                                             const short* __restrict__ B, int ldb,
                                             int K, short* As, short* Bs,
                                             f32x4 acc[4][4], int tid) {
    int wave = tid >> 6, lane = tid & 63;
    int lrow = lane >> 2;          // 0..15
    int lcol = (lane & 3) << 3;    // element offset 0,8,16,24
    // staging: wave w covers rows [w*32, w*32+32), two 16-row calls per matrix
    const short* ga0 = A + (size_t)(wave * 32 + lrow) * lda + lcol;
    const short* ga1 = ga0 + (size_t)16 * lda;
    const short* gb0 = B + (size_t)(wave * 32 + lrow) * ldb + lcol;
    const short* gb1 = gb0 + (size_t)16 * ldb;
    short* la0 = As + (wave * 32) * 32;
    short* la1 = As + (wave * 32 + 16) * 32;
    short* lb0 = Bs + (wave * 32) * 32;
    short* lb1 = Bs + (wave * 32 + 16) * 32;
    int mrow = (wave & 1) * 64 + (lane & 15);
    int ncol = (wave >> 1) * 64 + (lane & 15);
    int q8 = (lane >> 4) << 3;

    for (int k0 = 0; k0 < K; k0 += 32) {
        __syncthreads();   // protect LDS from overwrite while prev tile in use
        async16(ga0, la0);
        async16(ga1, la1);
        async16(gb0, lb0);
        async16(gb1, lb1);
        ga0 += 32; ga1 += 32; gb0 += 32; gb1 += 32;
        __syncthreads();   // compiler emits s_waitcnt vmcnt(0) before s_barrier
        short8 af[4], bf[4];
#pragma unroll
        for (int t = 0; t < 4; ++t) {
            af[t] = *(const short8*)(As + (mrow + t * 16) * 32 + q8);
            bf[t] = *(const short8*)(Bs + (ncol + t * 16) * 32 + q8);
        }
#pragma unroll
        for (int mt = 0; mt < 4; ++mt)
#pragma unroll
            for (int nt = 0; nt < 4; ++nt)
                acc[mt][nt] = __builtin_amdgcn_mfma_f32_16x16x32_bf16(af[mt], bf[nt],
                                                                      acc[mt][nt], 0, 0, 0);
    }
}
#define ACC_INIT {{{0.f,0.f,0.f,0.f},{0.f,0.f,0.f,0.f},{0.f,0.f,0.f,0.f},{0.f,0.f,0.f,0.f}}, \
                  {{0.f,0.f,0.f,0.f},{0.f,0.f,0.f,0.f},{0.f,0.f,0.f,0.f},{0.f,0.f,0.f,0.f}}, \
                  {{0.f,0.f,0.f,0.f},{0.f,0.f,0.f,0.f},{0.f,0.f,0.f,0.f},{0.f,0.f,0.f,0.f}}, \
                  {{0.f,0.f,0.f,0.f},{0.f,0.f,0.f,0.f},{0.f,0.f,0.f,0.f},{0.f,0.f,0.f,0.f}}}
// epilogue index helpers: row = (lane>>4)*4 + r (within 16), col = lane&15
#define EPI_GM(mt, r) (tile_m + (wave & 1) * 64 + (mt) * 16 + ((lane >> 4) << 2) + (r))
#define EPI_GN(nt)    (tile_n + (wave >> 1) * 64 + (nt) * 16 + (lane & 15))

// ---- fp32 -> bf16 pre-pass for query & encoder_states ----
__global__ __launch_bounds__(256) void convert_kernel(const float* __restrict__ q,
                                                      const float* __restrict__ e,
                                                      short* __restrict__ xq,
                                                      short* __restrict__ xe) {
    size_t i = (size_t)blockIdx.x * 256 + threadIdx.x;  // group of 8 elements
    const float* src = blockIdx.y ? e : q;
    short* dst = blockIdx.y ? xe : xq;
    float4 a = ((const float4*)src)[2 * i];
    float4 b = ((const float4*)src)[2 * i + 1];
    short8 v;
    v[0] = f2bf(a.x); v[1] = f2bf(a.y); v[2] = f2bf(a.z); v[3] = f2bf(a.w);
    v[4] = f2bf(b.x); v[5] = f2bf(b.y); v[6] = f2bf(b.z); v[7] = f2bf(b.w);
    ((short8*)dst)[i] = v;
}

// ---- W[F][H] fp32 -> Wt[H][F] bf16, z picks Wq/Wk/Wv ----
__global__ __launch_bounds__(256) void wtrans_kernel(const float* __restrict__ Wq,
                                                     const float* __restrict__ Wk,
                                                     const float* __restrict__ Wv,
                                                     short* __restrict__ Wt) {
    __shared__ float tile[32][33];
    const float* W = (blockIdx.z == 0) ? Wq : (blockIdx.z == 1) ? Wk : Wv;
    short* dst = Wt + (size_t)blockIdx.z * HD * FD;
    int h0 = blockIdx.x * 32, f0 = blockIdx.y * 32;
    int tx = threadIdx.x, ty = threadIdx.y;
    for (int j = ty; j < 32; j += 8)
        tile[j][tx] = W[(size_t)(f0 + j) * HD + h0 + tx];
    __syncthreads();
    for (int j = ty; j < 32; j += 8)
        dst[(size_t)(h0 + j) * FD + f0 + tx] = f2bf(tile[tx][j]);
}

// ---- projections: z=0: Q=Xq@WqT+bq; z=1: K=Xe@WkT+bk; z=2: Vt=(Xe@WvT+bv)^T ----
// XCD swizzle: all 8 n-blocks of an m-tile land on one XCD -> A-tile fetched once/XCD.
__global__ __launch_bounds__(256) void proj_kernel(const short* __restrict__ Xq,
                                                   const short* __restrict__ Xe,
                                                   const short* __restrict__ Wt3,
                                                   const float* __restrict__ bq,
                                                   const float* __restrict__ bk,
                                                   const float* __restrict__ bv,
                                                   short* __restrict__ Q, short* __restrict__ K,
                                                   short* __restrict__ Vt) {
    __shared__ short As[128 * 32];
    __shared__ short Bs[128 * 32];
    int tid = threadIdx.x;
    int wave = tid >> 6, lane = tid & 63;
    int p = blockIdx.z;
    const short* X = (p == 0) ? Xq : Xe;
    const short* Wt = Wt3 + (size_t)p * HD * FD;
    const float* bias = (p == 0) ? bq : (p == 1) ? bk : bv;
    int bid = blockIdx.x;              // 0..1023
    int xcd = bid & 7;
    int idx = bid >> 3;                // 0..127
    int n_t = idx & 7;                 // 8 n-tiles
    int m_t = (idx >> 3) * 8 + xcd;    // 128 m-tiles, grouped per XCD
    int tile_m = m_t * 128;
    int tile_n = n_t * 128;
    f32x4 acc[4][4] = ACC_INIT;
    gemm128_core(X + (size_t)tile_m * FD, FD, Wt + (size_t)tile_n * FD, FD, FD, As, Bs, acc, tid);
#pragma unroll
    for (int nt = 0; nt < 4; ++nt) {
        int gn = EPI_GN(nt);
        float bv_ = bias[gn];
#pragma unroll
        for (int mt = 0; mt < 4; ++mt)
#pragma unroll
            for (int r = 0; r < 4; ++r) {
                int gm = EPI_GM(mt, r);
                short val = f2bf(acc[mt][nt][r] + bv_);
                if (p == 0) {
                    Q[(size_t)gm * HD + gn] = val;
                } else if (p == 1) {
                    K[(size_t)gm * HD + gn] = val;
                } else {
                    int b = gm >> 11, t = gm & (TKv - 1);
                    Vt[((size_t)b * HD + gn) * TKv + t] = val;
                }
            }
    }
}

// ---- S[b][q][k] = (Q . K) / 32 masked (-inf), fp16 out ----
__global__ __launch_bounds__(256) void score_kernel(const short* __restrict__ Q,
                                                    const short* __restrict__ K,
                                                    const int* __restrict__ mask,
                                                    short* __restrict__ S) {
    __shared__ short As[128 * 32];
    __shared__ short Bs[128 * 32];
    int tid = threadIdx.x;
    int wave = tid >> 6, lane = tid & 63;
    int b = blockIdx.z;
    int tile_m = blockIdx.x * 128;
    int tile_n = blockIdx.y * 128;
    const short* Aq = Q + (size_t)b * TQv * HD;
    const short* Bk = K + (size_t)b * TKv * HD;
    f32x4 acc[4][4] = ACC_INIT;
    gemm128_core(Aq + (size_t)tile_m * HD, HD, Bk + (size_t)tile_n * HD, HD, HD, As, Bs, acc, tid);
    short* Sb = S + (size_t)b * TQv * TKv;
    const int* Mb = mask + (size_t)b * TQv * TKv;
#pragma unroll
    for (int mt = 0; mt < 4; ++mt)
#pragma unroll
        for (int r = 0; r < 4; ++r) {
            int gm = EPI_GM(mt, r);
#pragma unroll
            for (int nt = 0; nt < 4; ++nt) {
                int gn = EPI_GN(nt);
                int mk = Mb[(size_t)gm * TKv + gn];
                union { _Float16 h; short s; } cv;
                cv.h = (_Float16)(acc[mt][nt][r] * 0.03125f);
                Sb[(size_t)gm * TKv + gn] = mk ? cv.s : (short)0xFC00;  // -inf fp16
            }
        }
}

// ---- masked softmax per row: fp16 in (masked = -inf), bf16 P out in place ----
// one wave per row, no barriers
__global__ __launch_bounds__(256) void softmax_kernel(short* __restrict__ S) {
    int row = blockIdx.x * 4 + (threadIdx.x >> 6);
    int lane = threadIdx.x & 63;
    short* srow = S + (size_t)row * TKv;
    float v[32];
#pragma unroll
    for (int i = 0; i < 4; ++i) {
        half8 hv = *(const half8*)(srow + (i * 64 + lane) * 8);
#pragma unroll
        for (int j = 0; j < 8; ++j) v[i * 8 + j] = (float)hv[j];
    }
    float m = -1e30f;
#pragma unroll
    for (int i = 0; i < 32; ++i) m = fmaxf(m, v[i]);
    for (int s = 32; s > 0; s >>= 1) m = fmaxf(m, __shfl_xor(m, s));
    float sum = 0.f;
#pragma unroll
    for (int i = 0; i < 32; ++i) {
        float e = exp2f((v[i] - m) * 1.44269504f);  // -inf -> 0
        v[i] = e;
        sum += e;
    }
    for (int s = 32; s > 0; s >>= 1) sum += __shfl_xor(sum, s);
    float inv = (sum > 0.f) ? 1.f / sum : 0.f;
#pragma unroll
    for (int i = 0; i < 4; ++i) {
        short8 o;
#pragma unroll
        for (int j = 0; j < 8; ++j) o[j] = f2bf(v[i * 8 + j] * inv);
        *(short8*)(srow + (i * 64 + lane) * 8) = o;
    }
}

// ---- O[b][q][h] = sum_k P[b,q,k] * Vt[b,h,k], fp32 out ----
__global__ __launch_bounds__(256) void pv_kernel(const short* __restrict__ P,
                                                 const short* __restrict__ Vt,
                                                 float* __restrict__ Out) {
    __shared__ short As[128 * 32];
    __shared__ short Bs[128 * 32];
    int tid = threadIdx.x;
    int wave = tid >> 6, lane = tid & 63;
    int b = blockIdx.z;
    int tile_m = blockIdx.x * 128;
    int tile_n = blockIdx.y * 128;
    const short* Ap = P + (size_t)b * TQv * TKv;
    const short* Bv = Vt + (size_t)b * HD * TKv;
    f32x4 acc[4][4] = ACC_INIT;
    gemm128_core(Ap + (size_t)tile_m * TKv, TKv, Bv + (size_t)tile_n * TKv, TKv, TKv,
                 As, Bs, acc, tid);
    float* Ob = Out + (size_t)b * TQv * HD;
#pragma unroll
    for (int mt = 0; mt < 4; ++mt)
#pragma unroll
        for (int r = 0; r < 4; ++r) {
            int gm = EPI_GM(mt, r);
#pragma unroll
            for (int nt = 0; nt < 4; ++nt) {
                int gn = EPI_GN(nt);
                Ob[(size_t)gm * HD + gn] = acc[mt][nt][r];
            }
        }
}

extern "C" void kernel_launch(void* const* d_in, const int* in_sizes, int n_in,
                              void* d_out, int out_size, void* d_ws, size_t ws_size,
                              hipStream_t stream) {
    const float* query = (const float*)d_in[0];
    const float* enc   = (const float*)d_in[1];
    const int*   mask  = (const int*)d_in[2];
    const float* Wq    = (const float*)d_in[3];
    const float* bq    = (const float*)d_in[4];
    const float* Wk    = (const float*)d_in[5];
    const float* bk    = (const float*)d_in[6];
    const float* Wv    = (const float*)d_in[7];
    const float* bv    = (const float*)d_in[8];
    float* out = (float*)d_out;

    // workspace layout (bytes); total 174,063,616
    // S aliases Xq+Xe: X bf16 buffers are dead once proj_kernel completes.
    char* ws = (char*)d_ws;
    short* Wt = (short*)(ws);                  // 3 x [HD][FD] bf16       =  6,291,456
    short* Xq = (short*)(ws + 6291456);        // [NB*TQv][FD] bf16       = 33,554,432
    short* Xe = (short*)(ws + 39845888);       // [NB*TKv][FD] bf16       = 33,554,432
    short* S  = (short*)(ws + 6291456);        // [NB][TQv][TKv] fp16/bf16= 67,108,864 (aliases Xq,Xe)
    short* Qb = (short*)(ws + 73400320);       // [NB*TQv][HD] bf16       = 33,554,432
    short* Kb = (short*)(ws + 106954752);      // [NB*TKv][HD] bf16       = 33,554,432
    short* Vt = (short*)(ws + 140509184);      // [NB][HD][TKv] bf16      = 33,554,432
    (void)in_sizes; (void)n_in; (void)out_size; (void)ws_size;

    convert_kernel<<<dim3(8192, 2), 256, 0, stream>>>(query, enc, Xq, Xe);
    wtrans_kernel<<<dim3(32, 32, 3), dim3(32, 8), 0, stream>>>(Wq, Wk, Wv, Wt);
    proj_kernel<<<dim3(1024, 1, 3), 256, 0, stream>>>(Xq, Xe, Wt, bq, bk, bv, Qb, Kb, Vt);
    score_kernel<<<dim3(16, 16, 8), 256, 0, stream>>>(Qb, Kb, mask, S);
    softmax_kernel<<<dim3(NB * TQv / 4), 256, 0, stream>>>(S);
    pv_kernel<<<dim3(16, 8, 8), 256, 0, stream>>>(S, Vt, out);
}